// Round 1
// baseline (67969.574 us; speedup 1.0000x reference)
//
// LSTM 2-layer fused persistent kernel — Round 1 (correctness + structure).
// Design: pipelined layers (layer1 lags layer0 by 1 tick), 2049 global
// barriers total; bf16 MFMA 16x16x32 recurrent GEMM with weights resident in
// LDS; c-state in registers; two-level tick-indexed flag barrier.
// ws layout: Wcat 8MB | bcat | hbuf0/1 | grp/root flags | hseq(128MB) = ~137MB.
#include <hip/hip_runtime.h>
#include <hip/hip_bf16.h>
#include <cstdint>
#include <cstddef>

#define T_STEPS 2048
#define BATCH   64
#define HID     512
#define KDIM    1024      // concat K: [x(512) | h(512)]
#define GROWS   2048      // 4*H gate rows, interleaved (i,f,g,o) per h-col
#define NBLK    512       // 2 layers x 256 blocks
#define TPB     128       // 2 waves
#define NTICK   (T_STEPS + 1)

typedef float  f32x4 __attribute__((ext_vector_type(4)));
typedef short  s16x8 __attribute__((ext_vector_type(8)));

// ---- ws offsets (bytes) ----
#define WCAT_OFF   0x000000u   // 2*2048*1024*2 = 8 MiB bf16
#define BCAT_OFF   0x800000u   // 2*2048*4 = 16 KiB f32
#define HBUF0_OFF  0x810000u   // 2*64*512*2 = 128 KiB bf16 (double buffer, layer0)
#define HBUF1_OFF  0x830000u   // layer1
#define GRP_OFF    0x850000u   // 8*2049*4 = 64.1 KiB
#define ROOT_OFF   0x870000u   // 2049*4
#define HSEQ_OFF   0x900000u   // 2048*64*512*2 = 128 MiB bf16 (layer0 h sequence)

static __device__ __forceinline__ short f2bf(float v) {
  __hip_bfloat16 b = __float2bfloat16(v);
  return *reinterpret_cast<short*>(&b);
}
static __device__ __forceinline__ float sigm(float x) {
  return 1.0f / (1.0f + __expf(-x));
}

// ---------------- prep: gate-interleaved bf16 weights + fused bias ----------------
// Wcat[lay][r=4k+g][m] : m<512 -> Wx[g*512+k][m], m>=512 -> Wh[g*512+k][m-512]
__global__ void prep_weights(const float* __restrict__ Wx0, const float* __restrict__ Wh0,
                             const float* __restrict__ bx0, const float* __restrict__ bh0,
                             const float* __restrict__ Wx1, const float* __restrict__ Wh1,
                             const float* __restrict__ bx1, const float* __restrict__ bh1,
                             short* __restrict__ Wcat, float* __restrict__ bcat) {
  int idx = blockIdx.x * blockDim.x + threadIdx.x;
  const int total = 2 * GROWS * KDIM;
  if (idx >= total) return;
  int lay = idx / (GROWS * KDIM);
  int rem = idx % (GROWS * KDIM);
  int r = rem / KDIM, m = rem % KDIM;
  int k = r >> 2, g = r & 3;
  int srow = g * HID + k;
  const float* Wx = lay ? Wx1 : Wx0;
  const float* Wh = lay ? Wh1 : Wh0;
  float v = (m < 512) ? Wx[srow * 512 + m] : Wh[srow * HID + (m - 512)];
  Wcat[(size_t)lay * GROWS * KDIM + rem] = f2bf(v);
  if (m == 0) {
    const float* bx = lay ? bx1 : bx0;
    const float* bh = lay ? bh1 : bh0;
    bcat[lay * GROWS + r] = bx[srow] + bh[srow];
  }
}

__global__ void prep_h(const float* __restrict__ h0, short* __restrict__ hbuf0,
                       short* __restrict__ hbuf1) {
  int idx = blockIdx.x * blockDim.x + threadIdx.x;
  if (idx >= 2 * BATCH * HID) return;
  int lay = idx / (BATCH * HID);
  int rem = idx % (BATCH * HID);
  (lay ? hbuf1 : hbuf0)[rem] = f2bf(h0[idx]);  // parity-0 slot
}

// ---------------- fused persistent LSTM ----------------
struct KArgs {
  const float* x;      // [T,B,512] fp32
  const short* Wcat;   // [2][2048][1024] bf16
  const float* bcat;   // [2][2048]
  const float* c0;     // [2,B,H]
  short* hbuf0;        // [2][B][H] bf16 double buffer
  short* hbuf1;
  short* hseq;         // [T][B][H] bf16 layer0 output
  float* yout;         // d_out: [T,B,H] fp32
  float* hfin;         // d_out + T*B*H : [2,B,H]
  float* cfin;         // hfin + 2*B*H  : [2,B,H]
  int* grp;            // [8][NTICK]
  int* root;           // [NTICK]
};

#define MFMA(acc, af, bf) acc = __builtin_amdgcn_mfma_f32_16x16x32_bf16(af, bf, acc, 0, 0, 0)

__global__ __launch_bounds__(TPB) void lstm_fused(KArgs a) {
  // LDS weights: 16 gate-rows x 1024 k, +8 pad shorts (row stride 2064B = 4 banks
  // -> 2-way conflict on ds_read_b128 = free per m136)
  __shared__ short wl[16][1032];

  const int tid = threadIdx.x;
  const int bid = blockIdx.x;
  const int lay = bid >> 8;          // 0 or 1
  const int L = bid & 255;
  const int rowgroup = L >> 1;       // 0..127
  const int bhalf = L & 1;
  const int wv = tid >> 6;           // wave in block (2)
  const int l = tid & 63;
  const int lane15 = l & 15;
  const int jloc = l >> 4;           // 0..3
  const int koff = jloc << 3;        // assumed k sub-offset (consistent A/B -> correct)
  const int b = (bhalf * 2 + wv) * 16 + lane15;   // batch row this lane owns
  const int kcol = rowgroup * 4 + jloc;           // h column this lane owns
  const int row0 = rowgroup * 16;

  // --- one-time: weights -> LDS ---
  const short* __restrict__ W = a.Wcat + (size_t)lay * GROWS * KDIM;
  for (int i = tid; i < 2048; i += TPB) {          // 2048 chunks of 8 bf16
    int r = i >> 7;
    int kk = (i & 127) << 3;
    *reinterpret_cast<s16x8*>(&wl[r][kk]) =
        *reinterpret_cast<const s16x8*>(&W[(size_t)(row0 + r) * KDIM + kk]);
  }
  const float* bc = a.bcat + lay * GROWS + row0 + jloc * 4;
  const float bI = bc[0], bF = bc[1], bG = bc[2], bO = bc[3];
  float c = a.c0[lay * BATCH * HID + b * HID + kcol];
  short* hbuf = lay ? a.hbuf1 : a.hbuf0;
  __syncthreads();

  for (int tick = 0; tick < NTICK; ++tick) {
    const int t = tick - lay;                      // layer1 lags by 1
    if (t >= 0 && t < T_STEPS) {
      const short* __restrict__ hprev = hbuf + (t & 1) * BATCH * HID + b * HID;
      f32x4 acc0 = {0.f, 0.f, 0.f, 0.f}, acc1 = {0.f, 0.f, 0.f, 0.f};

      if (lay == 0) {                              // x-part from fp32 x, cvt to bf16
        const float* __restrict__ xp = a.x + ((size_t)t * BATCH + b) * 512;
#pragma unroll
        for (int ks = 0; ks < 16; ++ks) {
          const int kk = ks * 32 + koff;
          float4 v0 = *reinterpret_cast<const float4*>(xp + kk);
          float4 v1 = *reinterpret_cast<const float4*>(xp + kk + 4);
          s16x8 bfr;
          bfr[0] = f2bf(v0.x); bfr[1] = f2bf(v0.y); bfr[2] = f2bf(v0.z); bfr[3] = f2bf(v0.w);
          bfr[4] = f2bf(v1.x); bfr[5] = f2bf(v1.y); bfr[6] = f2bf(v1.z); bfr[7] = f2bf(v1.w);
          s16x8 afr = *reinterpret_cast<const s16x8*>(&wl[lane15][kk]);
          if (ks & 1) { MFMA(acc1, afr, bfr); } else { MFMA(acc0, afr, bfr); }
        }
      } else {                                     // x-part = layer0 h (bf16)
        const short* __restrict__ xp = a.hseq + ((size_t)t * BATCH + b) * HID;
#pragma unroll
        for (int ks = 0; ks < 16; ++ks) {
          const int kk = ks * 32 + koff;
          s16x8 bfr = *reinterpret_cast<const s16x8*>(xp + kk);
          s16x8 afr = *reinterpret_cast<const s16x8*>(&wl[lane15][kk]);
          if (ks & 1) { MFMA(acc1, afr, bfr); } else { MFMA(acc0, afr, bfr); }
        }
      }
#pragma unroll
      for (int ks = 16; ks < 32; ++ks) {           // h-part
        const int kk = ks * 32 + koff;
        s16x8 bfr = *reinterpret_cast<const s16x8*>(hprev + (kk - 512));
        s16x8 afr = *reinterpret_cast<const s16x8*>(&wl[lane15][kk]);
        if (ks & 1) { MFMA(acc1, afr, bfr); } else { MFMA(acc0, afr, bfr); }
      }

      // lane's 4 acc regs = gates (i,f,g,o) of its (b,kcol) — no cross-lane needed
      float gi = acc0[0] + acc1[0] + bI;
      float gf = acc0[1] + acc1[1] + bF;
      float gg = acc0[2] + acc1[2] + bG;
      float go = acc0[3] + acc1[3] + bO;
      float iv = sigm(gi), fv = sigm(gf);
      float gv = tanhf(gg), ov = sigm(go);
      c = fv * c + iv * gv;
      float hv = ov * tanhf(c);
      short hb = f2bf(hv);

      // publish h at agent scope (sc1 -> L3-coherent, keeps release wbl2 cheap)
      __hip_atomic_store((unsigned short*)&hbuf[((t + 1) & 1) * BATCH * HID + b * HID + kcol],
                         (unsigned short)hb, __ATOMIC_RELAXED, __HIP_MEMORY_SCOPE_AGENT);
      if (lay == 0) {
        __hip_atomic_store((unsigned short*)&a.hseq[((size_t)t * BATCH + b) * HID + kcol],
                           (unsigned short)hb, __ATOMIC_RELAXED, __HIP_MEMORY_SCOPE_AGENT);
      } else {
        __builtin_nontemporal_store(hv, &a.yout[((size_t)t * BATCH + b) * HID + kcol]);
      }
      if (t == T_STEPS - 1) {
        a.hfin[lay * BATCH * HID + b * HID + kcol] = hv;
        a.cfin[lay * BATCH * HID + b * HID + kcol] = c;
      }
    }

    // ---- global barrier (tick-indexed, two-level: 8 groups of 64) ----
    __syncthreads();                       // drains vmcnt (compiler emits waitcnt 0)
    if (tid == 0) {
      const int g = bid >> 6;
      int v = __hip_atomic_fetch_add(a.grp + g * NTICK + tick, 1,
                                     __ATOMIC_ACQ_REL, __HIP_MEMORY_SCOPE_AGENT);
      if (v == 63)
        __hip_atomic_fetch_add(a.root + tick, 1, __ATOMIC_ACQ_REL,
                               __HIP_MEMORY_SCOPE_AGENT);
      while (__hip_atomic_load(a.root + tick, __ATOMIC_RELAXED,
                               __HIP_MEMORY_SCOPE_AGENT) < 8)
        __builtin_amdgcn_s_sleep(1);
    }
    __syncthreads();
    __threadfence();   // acquire: L1+L2 inv on every wave before next-tick loads
  }
}

// ---------------- host launch ----------------
extern "C" void kernel_launch(void* const* d_in, const int* in_sizes, int n_in,
                              void* d_out, int out_size, void* d_ws, size_t ws_size,
                              hipStream_t stream) {
  const float* x   = (const float*)d_in[0];
  const float* h0  = (const float*)d_in[1];
  const float* c0  = (const float*)d_in[2];
  const float* Wx0 = (const float*)d_in[3];
  const float* Wh0 = (const float*)d_in[4];
  const float* bx0 = (const float*)d_in[5];
  const float* bh0 = (const float*)d_in[6];
  const float* Wx1 = (const float*)d_in[7];
  const float* Wh1 = (const float*)d_in[8];
  const float* bx1 = (const float*)d_in[9];
  const float* bh1 = (const float*)d_in[10];

  char* ws = (char*)d_ws;
  short* Wcat  = (short*)(ws + WCAT_OFF);
  float* bcat  = (float*)(ws + BCAT_OFF);
  short* hbuf0 = (short*)(ws + HBUF0_OFF);
  short* hbuf1 = (short*)(ws + HBUF1_OFF);
  int*   grp   = (int*)(ws + GRP_OFF);
  int*   root  = (int*)(ws + ROOT_OFF);
  short* hseq  = (short*)(ws + HSEQ_OFF);

  float* yout = (float*)d_out;
  float* hfin = yout + (size_t)T_STEPS * BATCH * HID;
  float* cfin = hfin + 2 * BATCH * HID;

  hipMemsetAsync(grp, 0, 8 * NTICK * sizeof(int), stream);
  hipMemsetAsync(root, 0, NTICK * sizeof(int), stream);

  {
    int total = 2 * GROWS * KDIM;
    prep_weights<<<(total + 255) / 256, 256, 0, stream>>>(Wx0, Wh0, bx0, bh0,
                                                          Wx1, Wh1, bx1, bh1,
                                                          Wcat, bcat);
  }
  {
    int total = 2 * BATCH * HID;
    prep_h<<<(total + 255) / 256, 256, 0, stream>>>(h0, hbuf0, hbuf1);
  }

  KArgs ka{x, Wcat, bcat, c0, hbuf0, hbuf1, hseq, yout, hfin, cfin, grp, root};
  void* params[] = {&ka};
  hipLaunchCooperativeKernel((void*)lstm_fused, dim3(NBLK), dim3(TPB), params, 0,
                             stream);
}

// Round 2
// 37686.597 us; speedup vs baseline: 1.8035x; 1.8035x over previous
//
// LSTM 2-layer fused persistent kernel — Round 2.
// R1 post-mortem: 33us/tick == 64 serialized same-address device atomics in the
// group barrier. Fix: all-broadcast flag barrier (1 release store/block, 128
// parallel pollers). Also: weights VGPR-resident (no LDS at all), 128 blocks x
// 512 thr, coherent h path via sc0/sc1 asm (no fences, x stays L2-cached),
// shfl-packed h stores.
// ws: hbuf1 128KB | flags 1.0MB | hs 128MB  (~135.5 MB total)
#include <hip/hip_runtime.h>
#include <hip/hip_bf16.h>
#include <cstdint>
#include <cstddef>

#define T_STEPS 2048
#define BATCH   64
#define HID     512
#define BH      (BATCH * HID)     // 32768
#define NBLK    128               // 2 layers x 64
#define TPB     512               // 8 waves: 2 M-tiles x 4 N-tiles
#define NTICK   (T_STEPS + 1)

typedef float        f32x4 __attribute__((ext_vector_type(4)));
typedef short        s16x8 __attribute__((ext_vector_type(8)));
typedef unsigned int u32x2 __attribute__((ext_vector_type(2)));

// ---- ws offsets (bytes) ----
#define HB1_OFF   0x000000u   // [2 parity][64][512] bf16 = 128 KiB (layer1 h dbuf)
#define FLAGS_OFF 0x020000u   // NTICK*NBLK*4 = 1,049,088 B
#define HS_OFF    0x130000u   // [T+1][64][512] bf16 = 128.06 MiB (layer0 h chain)

static __device__ __forceinline__ short f2bf(float v) {
  __hip_bfloat16 b = __float2bfloat16(v);
  return *reinterpret_cast<short*>(&b);
}
static __device__ __forceinline__ float sigm(float x) {
  return 1.0f / (1.0f + __expf(-x));
}

// coherent (L1+L2 bypass) 16B load: batched issue, waits done separately
#define LOADC16(dst, base, off)                                        \
  asm volatile("global_load_dwordx4 %0, %1, off offset:%c2 sc0 sc1"    \
               : "=v"(dst) : "v"(base), "i"(off))
// coherent 8B store
#define STOREC8(base, val)                                             \
  asm volatile("global_store_dwordx2 %0, %1, off sc0 sc1"              \
               :: "v"(base), "v"(val) : "memory")
#define VMDRAIN asm volatile("s_waitcnt vmcnt(0)" ::: "memory")

#define MFMA(acc, af, bf) \
  acc = __builtin_amdgcn_mfma_f32_16x16x32_bf16(af, bf, acc, 0, 0, 0)

__global__ void prep_h(const float* __restrict__ h0, short* __restrict__ hs,
                       short* __restrict__ hb1) {
  int idx = blockIdx.x * blockDim.x + threadIdx.x;
  if (idx >= 2 * BH) return;
  short v = f2bf(h0[idx]);
  if (idx < BH) hs[idx] = v;          // hs[0] = layer0 initial h
  else hb1[idx - BH] = v;             // hbuf1 parity-0 = layer1 initial h
}

struct KArgs {
  const float *x, *c0;
  const float *Wx0, *Wh0, *bx0, *bh0;
  const float *Wx1, *Wh1, *bx1, *bh1;
  short* hs;      // [T+1][B][H] bf16
  short* hb1;     // [2][B][H] bf16
  int* flags;     // [NTICK][NBLK]
  float *yout, *hfin, *cfin;
};

__global__ __launch_bounds__(TPB, 2) void lstm_fused(KArgs a) {
  const int tid = threadIdx.x, bid = blockIdx.x;
  const int lay = bid >> 6, bid32 = bid & 63;
  const int w = tid >> 6, mt = w >> 2, nt = w & 3;
  const int l = tid & 63, lane15 = l & 15, jloc = l >> 4, koff = jloc * 8;
  const int row0 = bid32 * 32 + mt * 16;          // gate-interleaved row base
  const int b = nt * 16 + lane15;                 // batch this lane owns
  const int kbase = row0 >> 2;                    // first h-col of this wave
  const int kcol = kbase + jloc;                  // h-col this lane owns

  const float* WxL = lay ? a.Wx1 : a.Wx0;
  const float* WhL = lay ? a.Wh1 : a.Wh0;
  const float* bxL = lay ? a.bx1 : a.bx0;
  const float* bhL = lay ? a.bh1 : a.bh0;

  // ---- one-time: weights -> VGPRs (gate-interleaved row r = 4k+g) ----
  const int r = row0 + lane15;
  const int srow = (r & 3) * HID + (r >> 2);      // row in Wx/Wh
  s16x8 wreg[32];
#pragma unroll
  for (int ks = 0; ks < 32; ++ks) {
    const float* src = (ks < 16)
        ? (WxL + (size_t)srow * 512 + ks * 32 + koff)
        : (WhL + (size_t)srow * 512 + (ks - 16) * 32 + koff);
    f32x4 v0 = *reinterpret_cast<const f32x4*>(src);
    f32x4 v1 = *reinterpret_cast<const f32x4*>(src + 4);
    s16x8 wv;
    wv[0] = f2bf(v0[0]); wv[1] = f2bf(v0[1]); wv[2] = f2bf(v0[2]); wv[3] = f2bf(v0[3]);
    wv[4] = f2bf(v1[0]); wv[5] = f2bf(v1[1]); wv[6] = f2bf(v1[2]); wv[7] = f2bf(v1[3]);
    wreg[ks] = wv;
  }
  const float bI = bxL[kcol]           + bhL[kcol];
  const float bF = bxL[HID + kcol]     + bhL[HID + kcol];
  const float bG = bxL[2 * HID + kcol] + bhL[2 * HID + kcol];
  const float bO = bxL[3 * HID + kcol] + bhL[3 * HID + kcol];
  float c = a.c0[lay * BH + b * HID + kcol];

  for (int tick = 0; tick < NTICK; ++tick) {
    const int t = tick - lay;                     // layer1 lags one tick
    if (t >= 0 && t < T_STEPS) {
      f32x4 acc0 = {0.f, 0.f, 0.f, 0.f}, acc1 = {0.f, 0.f, 0.f, 0.f};
      const short* hsrc = lay ? (a.hb1 + (t & 1) * BH) : (a.hs + (size_t)t * BH);
      const short* hp = hsrc + b * HID + koff;
      s16x8 hfrag[16];

      if (lay == 0) {
        // issue coherent h loads early; overlap with cached x loads + cvt + MFMA
#pragma unroll
        for (int i = 0; i < 16; ++i) LOADC16(hfrag[i], hp, i * 64);
        const float* xp = a.x + ((size_t)t * BATCH + b) * 512 + koff;
#pragma unroll
        for (int ks = 0; ks < 16; ++ks) {
          f32x4 v0 = *reinterpret_cast<const f32x4*>(xp + ks * 32);
          f32x4 v1 = *reinterpret_cast<const f32x4*>(xp + ks * 32 + 4);
          s16x8 bfr;
          bfr[0] = f2bf(v0[0]); bfr[1] = f2bf(v0[1]); bfr[2] = f2bf(v0[2]); bfr[3] = f2bf(v0[3]);
          bfr[4] = f2bf(v1[0]); bfr[5] = f2bf(v1[1]); bfr[6] = f2bf(v1[2]); bfr[7] = f2bf(v1[3]);
          if (ks & 1) { MFMA(acc1, wreg[ks], bfr); } else { MFMA(acc0, wreg[ks], bfr); }
        }
      } else {
        // x-operand = layer0 output hs[t+1] (published last tick), coherent
        const short* xp = a.hs + (size_t)(t + 1) * BH + b * HID + koff;
        s16x8 xfrag[16];
#pragma unroll
        for (int i = 0; i < 16; ++i) LOADC16(xfrag[i], xp, i * 64);
        VMDRAIN;
        __builtin_amdgcn_sched_barrier(0);
#pragma unroll
        for (int ks = 0; ks < 16; ++ks) {
          if (ks & 1) { MFMA(acc1, wreg[ks], xfrag[ks]); } else { MFMA(acc0, wreg[ks], xfrag[ks]); }
        }
#pragma unroll
        for (int i = 0; i < 16; ++i) LOADC16(hfrag[i], hp, i * 64);
      }
      VMDRAIN;
      __builtin_amdgcn_sched_barrier(0);
#pragma unroll
      for (int ks = 16; ks < 32; ++ks) {
        if (ks & 1) { MFMA(acc1, wreg[ks], hfrag[ks - 16]); } else { MFMA(acc0, wreg[ks], hfrag[ks - 16]); }
      }

      // lane's 4 acc regs = gates (i,f,g,o) of its (b,kcol)
      float gi = acc0[0] + acc1[0] + bI;
      float gf = acc0[1] + acc1[1] + bF;
      float gg = acc0[2] + acc1[2] + bG;
      float go = acc0[3] + acc1[3] + bO;
      float iv = sigm(gi), fv = sigm(gf);
      float gv = tanhf(gg), ov = sigm(go);
      c = fv * c + iv * gv;
      float hv = ov * tanhf(c);

      // pack 4 consecutive kcols (jloc 0..3, same b) into jloc0 lane -> 8B store
      int hvi = (int)(unsigned short)(unsigned short)f2bf(hv);
      int h1 = __shfl(hvi, lane15 + 16);
      int h2 = __shfl(hvi, lane15 + 32);
      int h3 = __shfl(hvi, lane15 + 48);
      short* dsth = lay ? (a.hb1 + ((t + 1) & 1) * BH + b * HID + kbase)
                        : (a.hs + (size_t)(t + 1) * BH + b * HID + kbase);
      if (jloc == 0) {
        u32x2 pk;
        pk[0] = (unsigned)(hvi & 0xffff) | ((unsigned)h1 << 16);
        pk[1] = (unsigned)(h2 & 0xffff) | ((unsigned)h3 << 16);
        STOREC8(dsth, pk);
      }
      if (lay == 1) {
        int f0 = __float_as_int(hv);
        int f1 = __shfl(f0, lane15 + 16);
        int f2 = __shfl(f0, lane15 + 32);
        int f3 = __shfl(f0, lane15 + 48);
        if (jloc == 0) {
          f32x4 yv = {__int_as_float(f0), __int_as_float(f1),
                      __int_as_float(f2), __int_as_float(f3)};
          __builtin_nontemporal_store(
              yv, reinterpret_cast<f32x4*>(a.yout + ((size_t)t * BATCH + b) * HID + kbase));
        }
      }
      if (t == T_STEPS - 1) {
        a.hfin[lay * BH + b * HID + kcol] = hv;
        a.cfin[lay * BH + b * HID + kcol] = c;
      }
    }

    // ---- all-broadcast flag barrier (tick-indexed, 1 store + 128 parallel polls) ----
    if (tick < NTICK - 1) {
      VMDRAIN;                         // drain our asm stores (compiler can't track them)
      __syncthreads();
      if (tid == 0)
        __hip_atomic_store(a.flags + (size_t)tick * NBLK + bid, 1,
                           __ATOMIC_RELEASE, __HIP_MEMORY_SCOPE_AGENT);
      if (tid < NBLK) {
        while (__hip_atomic_load(a.flags + (size_t)tick * NBLK + tid,
                                 __ATOMIC_RELAXED, __HIP_MEMORY_SCOPE_AGENT) == 0)
          __builtin_amdgcn_s_sleep(1);
      }
      __syncthreads();
    }
  }
}

// ---------------- host launch ----------------
extern "C" void kernel_launch(void* const* d_in, const int* in_sizes, int n_in,
                              void* d_out, int out_size, void* d_ws, size_t ws_size,
                              hipStream_t stream) {
  const float* x   = (const float*)d_in[0];
  const float* h0  = (const float*)d_in[1];
  const float* c0  = (const float*)d_in[2];
  const float* Wx0 = (const float*)d_in[3];
  const float* Wh0 = (const float*)d_in[4];
  const float* bx0 = (const float*)d_in[5];
  const float* bh0 = (const float*)d_in[6];
  const float* Wx1 = (const float*)d_in[7];
  const float* Wh1 = (const float*)d_in[8];
  const float* bx1 = (const float*)d_in[9];
  const float* bh1 = (const float*)d_in[10];

  char* ws = (char*)d_ws;
  short* hb1  = (short*)(ws + HB1_OFF);
  int* flags  = (int*)(ws + FLAGS_OFF);
  short* hs   = (short*)(ws + HS_OFF);

  float* yout = (float*)d_out;
  float* hfin = yout + (size_t)T_STEPS * BH;
  float* cfin = hfin + 2 * BH;

  hipMemsetAsync(flags, 0, (size_t)NBLK * NTICK * sizeof(int), stream);
  prep_h<<<(2 * BH + 255) / 256, 256, 0, stream>>>(h0, hs, hb1);

  KArgs ka{x, c0, Wx0, Wh0, bx0, bh0, Wx1, Wh1, bx1, bh1,
           hs, hb1, flags, yout, hfin, cfin};
  void* params[] = {&ka};
  hipLaunchCooperativeKernel((void*)lstm_fused, dim3(NBLK), dim3(TPB), params, 0,
                             stream);
}

// Round 3
// 32467.560 us; speedup vs baseline: 2.0935x; 1.1607x over previous
//
// LSTM 2-layer fused persistent kernel — Round 3.
// R2 post-mortem: 18us/tick = agent-scope RELEASE store emits buffer_wbl2
// (full dirty-L2 writeback, us-scale, every block every tick) since XCD L2s
// are non-coherent. Fix: NO atomic builtins / fences in the loop. All
// cross-block data goes sc0/sc1 write-through (coherence point = MALL);
// barrier = vmcnt(0) drain + raw sc0sc1 flag store; pollers use sc0sc1 loads.
// Also: layers fully decoupled — layer0 only waits on layer0 flags (sprints
// ahead); layer1 polls layer0's tick-t flags + its own.
// ws: hb1 128KB | flags 1MB | hs 128MB  (~135.5 MB)
#include <hip/hip_runtime.h>
#include <hip/hip_bf16.h>
#include <cstdint>
#include <cstddef>

#define T_STEPS 2048
#define BATCH   64
#define HID     512
#define BH      (BATCH * HID)     // 32768
#define NBLK    128               // 2 layers x 64
#define TPB     512               // 8 waves: 2 M-tiles x 4 N-tiles

typedef float        f32x4 __attribute__((ext_vector_type(4)));
typedef short        s16x8 __attribute__((ext_vector_type(8)));
typedef int          i32x4 __attribute__((ext_vector_type(4)));
typedef unsigned int u32x2 __attribute__((ext_vector_type(2)));

// ---- ws offsets (bytes) ----
#define HB1_OFF   0x000000u   // [2 parity][64][512] bf16 = 128 KiB (layer1 h dbuf)
#define FLAGS_OFF 0x020000u   // 2 * T_STEPS * 64 * 4 = 1 MiB
#define HS_OFF    0x130000u   // [T+1][64][512] bf16 = 128.06 MiB (layer0 h chain)

static __device__ __forceinline__ short f2bf(float v) {
  __hip_bfloat16 b = __float2bfloat16(v);
  return *reinterpret_cast<short*>(&b);
}
static __device__ __forceinline__ float sigm(float x) {
  return 1.0f / (1.0f + __expf(-x));
}

// coherent (L1+L2 bypass -> MALL) 16B load; batched issue, wait separately
#define LOADC16(dst, base, off)                                        \
  asm volatile("global_load_dwordx4 %0, %1, off offset:%c2 sc0 sc1"    \
               : "=v"(dst) : "v"(base), "i"(off))
// coherent 8B store (write-through to MALL)
#define STOREC8(base, val)                                             \
  asm volatile("global_store_dwordx2 %0, %1, off sc0 sc1"              \
               :: "v"(base), "v"(val) : "memory")
#define VMDRAIN asm volatile("s_waitcnt vmcnt(0)" ::: "memory")

#define MFMA(acc, af, bf) \
  acc = __builtin_amdgcn_mfma_f32_16x16x32_bf16(af, bf, acc, 0, 0, 0)

// spin on 4 flags (one dwordx4) until all nonzero; sc0sc1 -> reads MALL
static __device__ __forceinline__ void poll4(const int* p) {
  i32x4 v;
  for (;;) {
    asm volatile("global_load_dwordx4 %0, %1, off sc0 sc1\n\t"
                 "s_waitcnt vmcnt(0)"
                 : "=v"(v) : "v"(p) : "memory");
    if ((v[0] & v[1] & v[2] & v[3]) != 0) return;
    __builtin_amdgcn_s_sleep(1);
  }
}

__global__ void prep_h(const float* __restrict__ h0, short* __restrict__ hs,
                       short* __restrict__ hb1) {
  int idx = blockIdx.x * blockDim.x + threadIdx.x;
  if (idx >= 2 * BH) return;
  short v = f2bf(h0[idx]);
  if (idx < BH) hs[idx] = v;          // hs[0] = layer0 initial h
  else hb1[idx - BH] = v;             // hb1 parity-0 = layer1 initial h
}

struct KArgs {
  const float *x, *c0;
  const float *Wx0, *Wh0, *bx0, *bh0;
  const float *Wx1, *Wh1, *bx1, *bh1;
  short* hs;      // [T+1][B][H] bf16 (layer0 h chain; slot t = h at time t)
  short* hb1;     // [2][B][H] bf16 (layer1 h double buffer)
  int* flags;     // [2][T][64]
  float *yout, *hfin, *cfin;
};

template <int LAY>
static __device__ __forceinline__ void run_layer(const KArgs& a, int bid32,
                                                 int tid) {
  const int w = tid >> 6, mt = w >> 2, nt = w & 3;
  const int l = tid & 63, lane15 = l & 15, jloc = l >> 4, koff = jloc * 8;
  const int row0 = bid32 * 32 + mt * 16;          // gate-interleaved row base
  const int b = nt * 16 + lane15;                 // batch this lane owns
  const int kbase = row0 >> 2;                    // first h-col of this wave
  const int kcol = kbase + jloc;                  // h-col this lane owns

  const float* WxL = LAY ? a.Wx1 : a.Wx0;
  const float* WhL = LAY ? a.Wh1 : a.Wh0;
  const float* bxL = LAY ? a.bx1 : a.bx0;
  const float* bhL = LAY ? a.bh1 : a.bh0;

  // ---- one-time: weights -> VGPRs (gate-interleaved row r = 4k+g) ----
  const int r = row0 + lane15;
  const int srow = (r & 3) * HID + (r >> 2);      // row in Wx/Wh
  s16x8 wreg[32];
#pragma unroll
  for (int ks = 0; ks < 32; ++ks) {
    const float* src = (ks < 16)
        ? (WxL + (size_t)srow * 512 + ks * 32 + koff)
        : (WhL + (size_t)srow * 512 + (ks - 16) * 32 + koff);
    f32x4 v0 = *reinterpret_cast<const f32x4*>(src);
    f32x4 v1 = *reinterpret_cast<const f32x4*>(src + 4);
    s16x8 wv;
    wv[0] = f2bf(v0[0]); wv[1] = f2bf(v0[1]); wv[2] = f2bf(v0[2]); wv[3] = f2bf(v0[3]);
    wv[4] = f2bf(v1[0]); wv[5] = f2bf(v1[1]); wv[6] = f2bf(v1[2]); wv[7] = f2bf(v1[3]);
    wreg[ks] = wv;
  }
  const float bI = bxL[kcol]           + bhL[kcol];
  const float bF = bxL[HID + kcol]     + bhL[HID + kcol];
  const float bG = bxL[2 * HID + kcol] + bhL[2 * HID + kcol];
  const float bO = bxL[3 * HID + kcol] + bhL[3 * HID + kcol];
  float c = a.c0[LAY * BH + b * HID + kcol];

  int* f0 = a.flags;                       // [T][64] layer0 flags
  int* f1 = a.flags + (size_t)T_STEPS * 64;  // layer1 flags

  for (int t = 0; t < T_STEPS; ++t) {
    // ---- wait for producers (parallel distinct-flag polls, no RMW) ----
    if (LAY == 0) {
      if (t > 0 && tid < 16) poll4(f0 + (size_t)(t - 1) * 64 + tid * 4);
    } else {
      if (tid < 16) poll4(f0 + (size_t)t * 64 + tid * 4);       // hs[t+1] ready
      else if (t > 0 && tid < 32)
        poll4(f1 + (size_t)(t - 1) * 64 + (tid - 16) * 4);      // own h ready
    }
    __syncthreads();

    f32x4 acc0 = {0.f, 0.f, 0.f, 0.f}, acc1 = {0.f, 0.f, 0.f, 0.f};
    const short* hp = (LAY ? a.hb1 + (t & 1) * BH : a.hs + (size_t)t * BH)
                      + b * HID + koff;
    s16x8 hfrag[16];
#pragma unroll
    for (int i = 0; i < 16; ++i) LOADC16(hfrag[i], hp, i * 64);

    if (LAY == 0) {
      // x-part from fp32 input, L2-cached compiler loads; overlaps h latency
      const float* xp = a.x + ((size_t)t * BATCH + b) * 512 + koff;
#pragma unroll
      for (int ks = 0; ks < 16; ++ks) {
        f32x4 v0 = *reinterpret_cast<const f32x4*>(xp + ks * 32);
        f32x4 v1 = *reinterpret_cast<const f32x4*>(xp + ks * 32 + 4);
        s16x8 bfr;
        bfr[0] = f2bf(v0[0]); bfr[1] = f2bf(v0[1]); bfr[2] = f2bf(v0[2]); bfr[3] = f2bf(v0[3]);
        bfr[4] = f2bf(v1[0]); bfr[5] = f2bf(v1[1]); bfr[6] = f2bf(v1[2]); bfr[7] = f2bf(v1[3]);
        if (ks & 1) { MFMA(acc1, wreg[ks], bfr); } else { MFMA(acc0, wreg[ks], bfr); }
      }
    } else {
      // x-operand = layer0 output hs[t+1] (coherent)
      const short* xp = a.hs + (size_t)(t + 1) * BH + b * HID + koff;
      s16x8 xfrag[16];
#pragma unroll
      for (int i = 0; i < 16; ++i) LOADC16(xfrag[i], xp, i * 64);
      VMDRAIN;
      __builtin_amdgcn_sched_barrier(0);
#pragma unroll
      for (int ks = 0; ks < 16; ++ks) {
        if (ks & 1) { MFMA(acc1, wreg[ks], xfrag[ks]); } else { MFMA(acc0, wreg[ks], xfrag[ks]); }
      }
    }
    VMDRAIN;                               // hfrag complete
    __builtin_amdgcn_sched_barrier(0);
#pragma unroll
    for (int ks = 16; ks < 32; ++ks) {
      if (ks & 1) { MFMA(acc1, wreg[ks], hfrag[ks - 16]); } else { MFMA(acc0, wreg[ks], hfrag[ks - 16]); }
    }

    // lane's 4 acc regs = gates (i,f,g,o) of its (b,kcol)
    float gi = acc0[0] + acc1[0] + bI;
    float gf = acc0[1] + acc1[1] + bF;
    float gg = acc0[2] + acc1[2] + bG;
    float go = acc0[3] + acc1[3] + bO;
    float iv = sigm(gi), fv = sigm(gf);
    float gv = tanhf(gg), ov = sigm(go);
    c = fv * c + iv * gv;
    float hv = ov * tanhf(c);

    // pack 4 consecutive kcols (jloc 0..3, same b) into jloc0 lane -> 8B store
    int hvi = (int)(unsigned short)f2bf(hv);
    int h1 = __shfl(hvi, lane15 + 16);
    int h2 = __shfl(hvi, lane15 + 32);
    int h3 = __shfl(hvi, lane15 + 48);
    short* dsth = (LAY ? a.hb1 + ((t + 1) & 1) * BH : a.hs + (size_t)(t + 1) * BH)
                  + b * HID + kbase;
    if (jloc == 0) {
      u32x2 pk;
      pk[0] = (unsigned)(hvi & 0xffff) | ((unsigned)h1 << 16);
      pk[1] = (unsigned)(h2 & 0xffff) | ((unsigned)h3 << 16);
      STOREC8(dsth, pk);
    }
    if (LAY == 1) {
      int y0 = __float_as_int(hv);
      int y1 = __shfl(y0, lane15 + 16);
      int y2 = __shfl(y0, lane15 + 32);
      int y3 = __shfl(y0, lane15 + 48);
      if (jloc == 0) {
        f32x4 yv = {__int_as_float(y0), __int_as_float(y1),
                    __int_as_float(y2), __int_as_float(y3)};
        __builtin_nontemporal_store(
            yv, reinterpret_cast<f32x4*>(a.yout + ((size_t)t * BATCH + b) * HID + kbase));
      }
    }
    if (t == T_STEPS - 1) {
      a.hfin[LAY * BH + b * HID + kcol] = hv;
      a.cfin[LAY * BH + b * HID + kcol] = c;
    }

    // ---- release: drain write-through stores, then raw flag store ----
    VMDRAIN;
    __syncthreads();
    if (tid == 0) {
      int one = 1;
      int* fp = (LAY ? f1 : f0) + (size_t)t * 64 + bid32;
      asm volatile("global_store_dword %0, %1, off sc0 sc1"
                   :: "v"(fp), "v"(one) : "memory");
    }
  }
}

__global__ __launch_bounds__(TPB, 2) void lstm_fused(KArgs a) {
  const int bid = blockIdx.x;
  if (bid < 64) run_layer<0>(a, bid, threadIdx.x);
  else          run_layer<1>(a, bid - 64, threadIdx.x);
}

// ---------------- host launch ----------------
extern "C" void kernel_launch(void* const* d_in, const int* in_sizes, int n_in,
                              void* d_out, int out_size, void* d_ws, size_t ws_size,
                              hipStream_t stream) {
  const float* x   = (const float*)d_in[0];
  const float* h0  = (const float*)d_in[1];
  const float* c0  = (const float*)d_in[2];
  const float* Wx0 = (const float*)d_in[3];
  const float* Wh0 = (const float*)d_in[4];
  const float* bx0 = (const float*)d_in[5];
  const float* bh0 = (const float*)d_in[6];
  const float* Wx1 = (const float*)d_in[7];
  const float* Wh1 = (const float*)d_in[8];
  const float* bx1 = (const float*)d_in[9];
  const float* bh1 = (const float*)d_in[10];

  char* ws = (char*)d_ws;
  short* hb1  = (short*)(ws + HB1_OFF);
  int* flags  = (int*)(ws + FLAGS_OFF);
  short* hs   = (short*)(ws + HS_OFF);

  float* yout = (float*)d_out;
  float* hfin = yout + (size_t)T_STEPS * BH;
  float* cfin = hfin + 2 * BH;

  hipMemsetAsync(flags, 0, (size_t)2 * T_STEPS * 64 * sizeof(int), stream);
  prep_h<<<(2 * BH + 255) / 256, 256, 0, stream>>>(h0, hs, hb1);

  KArgs ka{x, c0, Wx0, Wh0, bx0, bh0, Wx1, Wh1, bx1, bh1,
           hs, hb1, flags, yout, hfin, cfin};
  void* params[] = {&ka};
  hipLaunchCooperativeKernel((void*)lstm_fused, dim3(NBLK), dim3(TPB), params, 0,
                             stream);
}

// Round 5
// 16832.733 us; speedup vs baseline: 4.0379x; 1.9288x over previous
//
// LSTM 2-layer fused persistent kernel — Round 5.
// R4 post-mortem: grid(256) == cooperative capacity (1 blk/CU at ~300 VGPR)
// -> launch silently rejected, output zeros. Fix: __launch_bounds__(256,2)
// (VGPR cap 256 -> 2 blk/CU -> capacity 512) + register diet so nothing
// spills: x pre-converted to bf16 (prep_xb), single frag[16] reused for
// x-phase then h-phase (~215 VGPR). Layer0 h-chain -> 16-slot ring (L0
// throttles on f1[t-16]) so xb fits ws. Barrier scheme = R3 (proven).
// ws: hb1 128KB | flags 2MB | hs-ring 1MB | xb 128MB  (~138.4 MB)
#include <hip/hip_runtime.h>
#include <hip/hip_bf16.h>
#include <cstdint>
#include <cstddef>

#define T_STEPS 2048
#define BATCH   64
#define HID     512
#define BH      (BATCH * HID)     // 32768
#define NBLK    256               // 2 layers x 128 blocks (16 gate-rows each)
#define TPB     256               // 4 waves: batch split 4 x 16
#define NBLK_L  128               // blocks per layer
#define RING    16                // layer0 h ring slots (pow2)

typedef float        f32x4 __attribute__((ext_vector_type(4)));
typedef short        s16x8 __attribute__((ext_vector_type(8)));
typedef int          i32x4 __attribute__((ext_vector_type(4)));
typedef unsigned int u32x2 __attribute__((ext_vector_type(2)));

// ---- ws offsets (bytes) ----
#define HB1_OFF   0x000000u   // [2 parity][64][512] bf16 = 128 KiB (layer1 h dbuf)
#define FLAGS_OFF 0x020000u   // 2 * 2048 * 128 * 4 = 2 MiB
#define HS_OFF    0x230000u   // [RING][64][512] bf16 = 1 MiB (layer0 h ring)
#define XB_OFF    0x400000u   // [T][64][512] bf16 = 128 MiB
// end = 0x8400000 = 138.4 MB (R1 proved >=143 MB usable)

static __device__ __forceinline__ short f2bf(float v) {
  __hip_bfloat16 b = __float2bfloat16(v);
  return *reinterpret_cast<short*>(&b);
}
static __device__ __forceinline__ float sigm(float x) {
  return 1.0f / (1.0f + __expf(-x));
}

// coherent (L1+L2 bypass -> coherence point) 16B load; batch issue, wait later
#define LOADC16(dst, base, off)                                        \
  asm volatile("global_load_dwordx4 %0, %1, off offset:%c2 sc0 sc1"    \
               : "=v"(dst) : "v"(base), "i"(off))
// coherent 8B store (write-through)
#define STOREC8(base, val)                                             \
  asm volatile("global_store_dwordx2 %0, %1, off sc0 sc1"              \
               :: "v"(base), "v"(val) : "memory")
#define VMDRAIN asm volatile("s_waitcnt vmcnt(0)" ::: "memory")

#define MFMA(acc, af, bf) \
  acc = __builtin_amdgcn_mfma_f32_16x16x32_bf16(af, bf, acc, 0, 0, 0)

// spin on 4 flags (one dwordx4) until all nonzero
static __device__ __forceinline__ void poll4(const int* p) {
  i32x4 v;
  for (;;) {
    asm volatile("global_load_dwordx4 %0, %1, off sc0 sc1\n\t"
                 "s_waitcnt vmcnt(0)"
                 : "=v"(v) : "v"(p) : "memory");
    if ((v[0] & v[1] & v[2] & v[3]) != 0) return;
    __builtin_amdgcn_s_sleep(1);
  }
}

__global__ void prep_h(const float* __restrict__ h0, short* __restrict__ hs,
                       short* __restrict__ hb1) {
  int idx = blockIdx.x * blockDim.x + threadIdx.x;
  if (idx >= 2 * BH) return;
  short v = f2bf(h0[idx]);
  if (idx < BH) hs[idx] = v;          // hs ring slot 0 = layer0 initial h
  else hb1[idx - BH] = v;             // hb1 parity-0 = layer1 initial h
}

__global__ void prep_xb(const float* __restrict__ x, short* __restrict__ xb) {
  size_t i = ((size_t)blockIdx.x * blockDim.x + threadIdx.x) * 8;
  if (i >= (size_t)T_STEPS * BH) return;
  f32x4 v0 = *reinterpret_cast<const f32x4*>(x + i);
  f32x4 v1 = *reinterpret_cast<const f32x4*>(x + i + 4);
  s16x8 o;
  o[0] = f2bf(v0[0]); o[1] = f2bf(v0[1]); o[2] = f2bf(v0[2]); o[3] = f2bf(v0[3]);
  o[4] = f2bf(v1[0]); o[5] = f2bf(v1[1]); o[6] = f2bf(v1[2]); o[7] = f2bf(v1[3]);
  *reinterpret_cast<s16x8*>(xb + i) = o;
}

struct KArgs {
  const short* xb;   // [T][B][H] bf16
  const float* c0;
  const float *Wx0, *Wh0, *bx0, *bh0;
  const float *Wx1, *Wh1, *bx1, *bh1;
  short* hs;      // [RING][B][H] bf16 ring; slot (t)&15 = layer0 h at time t
  short* hb1;     // [2][B][H] bf16 (layer1 h double buffer)
  int* flags;     // [2][T][128]
  float *yout, *hfin, *cfin;
};

template <int LAY>
static __device__ __forceinline__ void run_layer(const KArgs& a, int bidL,
                                                 int tid) {
  const int nt = tid >> 6;                        // batch tile 0..3
  const int l = tid & 63, lane15 = l & 15, jloc = l >> 4, koff = jloc * 8;
  const int row0 = bidL * 16;                     // gate-interleaved row base
  const int b = nt * 16 + lane15;                 // batch this lane owns
  const int kbase = row0 >> 2;                    // first h-col of this block
  const int kcol = kbase + jloc;                  // h-col this lane owns

  const float* WxL = LAY ? a.Wx1 : a.Wx0;
  const float* WhL = LAY ? a.Wh1 : a.Wh0;
  const float* bxL = LAY ? a.bx1 : a.bx0;
  const float* bhL = LAY ? a.bh1 : a.bh0;

  // ---- one-time: weights -> VGPRs (gate-interleaved row r = 4k+g) ----
  const int r = row0 + lane15;
  const int srow = (r & 3) * HID + (r >> 2);      // row in Wx/Wh
  s16x8 wreg[32];
#pragma unroll
  for (int ks = 0; ks < 32; ++ks) {
    const float* src = (ks < 16)
        ? (WxL + (size_t)srow * 512 + ks * 32 + koff)
        : (WhL + (size_t)srow * 512 + (ks - 16) * 32 + koff);
    f32x4 v0 = *reinterpret_cast<const f32x4*>(src);
    f32x4 v1 = *reinterpret_cast<const f32x4*>(src + 4);
    s16x8 wv;
    wv[0] = f2bf(v0[0]); wv[1] = f2bf(v0[1]); wv[2] = f2bf(v0[2]); wv[3] = f2bf(v0[3]);
    wv[4] = f2bf(v1[0]); wv[5] = f2bf(v1[1]); wv[6] = f2bf(v1[2]); wv[7] = f2bf(v1[3]);
    wreg[ks] = wv;
  }
  const float bI = bxL[kcol]           + bhL[kcol];
  const float bF = bxL[HID + kcol]     + bhL[HID + kcol];
  const float bG = bxL[2 * HID + kcol] + bhL[2 * HID + kcol];
  const float bO = bxL[3 * HID + kcol] + bhL[3 * HID + kcol];
  float c = a.c0[LAY * BH + b * HID + kcol];

  int* f0 = a.flags;                             // [T][128] layer0 flags
  int* f1 = a.flags + (size_t)T_STEPS * NBLK_L;  // layer1 flags

  for (int t = 0; t < T_STEPS; ++t) {
    // ---- wait for producers (parallel distinct-flag polls, no RMW) ----
    if (LAY == 0) {
      if (t > 0 && tid < 32) poll4(f0 + (size_t)(t - 1) * NBLK_L + tid * 4);
      if (t >= RING && tid >= 32 && tid < 64)    // ring-slot reuse throttle
        poll4(f1 + (size_t)(t - RING) * NBLK_L + (tid - 32) * 4);
    } else {
      if (tid < 32) poll4(f0 + (size_t)t * NBLK_L + tid * 4);    // x ready
      else if (t > 0 && tid < 64)
        poll4(f1 + (size_t)(t - 1) * NBLK_L + (tid - 32) * 4);   // own h ready
    }
    __syncthreads();

    f32x4 acc0 = {0.f, 0.f, 0.f, 0.f}, acc1 = {0.f, 0.f, 0.f, 0.f};
    s16x8 frag[16];

    // ---- phase X: frag <= x operand ----
    if (LAY == 0) {
      const short* xp = a.xb + ((size_t)t * BATCH + b) * HID + koff;
#pragma unroll
      for (int i = 0; i < 16; ++i)
        frag[i] = *reinterpret_cast<const s16x8*>(xp + i * 32);   // cached
    } else {
      const short* xp = a.hs + (size_t)((t + 1) & (RING - 1)) * BH
                        + b * HID + koff;                          // coherent
#pragma unroll
      for (int i = 0; i < 16; ++i) LOADC16(frag[i], xp, i * 64);
      VMDRAIN;
      __builtin_amdgcn_sched_barrier(0);
    }
#pragma unroll
    for (int ks = 0; ks < 16; ++ks) {
      if (ks & 1) { MFMA(acc1, wreg[ks], frag[ks]); } else { MFMA(acc0, wreg[ks], frag[ks]); }
    }

    // ---- phase H: frag <= h operand (reuse regs; WAR safe: issued after
    // MFMAs, writeback >=150cy later) ----
    const short* hp = (LAY ? a.hb1 + (t & 1) * BH
                           : a.hs + (size_t)(t & (RING - 1)) * BH)
                      + b * HID + koff;
#pragma unroll
    for (int i = 0; i < 16; ++i) LOADC16(frag[i], hp, i * 64);
    VMDRAIN;
    __builtin_amdgcn_sched_barrier(0);
#pragma unroll
    for (int ks = 16; ks < 32; ++ks) {
      if (ks & 1) { MFMA(acc1, wreg[ks], frag[ks - 16]); } else { MFMA(acc0, wreg[ks], frag[ks - 16]); }
    }

    // lane's 4 acc regs = gates (i,f,g,o) of its (b,kcol)
    float gi = acc0[0] + acc1[0] + bI;
    float gf = acc0[1] + acc1[1] + bF;
    float gg = acc0[2] + acc1[2] + bG;
    float go = acc0[3] + acc1[3] + bO;
    float iv = sigm(gi), fv = sigm(gf);
    float gv = tanhf(gg), ov = sigm(go);
    c = fv * c + iv * gv;
    float hv = ov * tanhf(c);

    // pack 4 consecutive kcols (jloc 0..3, same b) into jloc0 lane -> 8B store
    int hvi = (int)(unsigned short)f2bf(hv);
    int h1 = __shfl(hvi, lane15 + 16);
    int h2 = __shfl(hvi, lane15 + 32);
    int h3 = __shfl(hvi, lane15 + 48);
    short* dsth = (LAY ? a.hb1 + ((t + 1) & 1) * BH
                       : a.hs + (size_t)((t + 1) & (RING - 1)) * BH)
                  + b * HID + kbase;
    if (jloc == 0) {
      u32x2 pk;
      pk[0] = (unsigned)(hvi & 0xffff) | ((unsigned)h1 << 16);
      pk[1] = (unsigned)(h2 & 0xffff) | ((unsigned)h3 << 16);
      STOREC8(dsth, pk);
    }
    if (LAY == 1) {
      int y0 = __float_as_int(hv);
      int y1 = __shfl(y0, lane15 + 16);
      int y2 = __shfl(y0, lane15 + 32);
      int y3 = __shfl(y0, lane15 + 48);
      if (jloc == 0) {
        f32x4 yv = {__int_as_float(y0), __int_as_float(y1),
                    __int_as_float(y2), __int_as_float(y3)};
        __builtin_nontemporal_store(
            yv, reinterpret_cast<f32x4*>(a.yout + ((size_t)t * BATCH + b) * HID + kbase));
      }
    }
    if (t == T_STEPS - 1) {
      a.hfin[LAY * BH + b * HID + kcol] = hv;
      a.cfin[LAY * BH + b * HID + kcol] = c;
    }

    // ---- release: drain write-through stores, then raw flag store ----
    VMDRAIN;
    __syncthreads();
    if (tid == 0) {
      int one = 1;
      int* fp = (LAY ? f1 : f0) + (size_t)t * NBLK_L + bidL;
      asm volatile("global_store_dword %0, %1, off sc0 sc1"
                   :: "v"(fp), "v"(one) : "memory");
    }
  }
}

__global__ __launch_bounds__(TPB, 2) void lstm_fused(KArgs a) {
  const int bid = blockIdx.x;
  if (bid < NBLK_L) run_layer<0>(a, bid, threadIdx.x);
  else              run_layer<1>(a, bid - NBLK_L, threadIdx.x);
}

// ---------------- host launch ----------------
extern "C" void kernel_launch(void* const* d_in, const int* in_sizes, int n_in,
                              void* d_out, int out_size, void* d_ws, size_t ws_size,
                              hipStream_t stream) {
  const float* x   = (const float*)d_in[0];
  const float* h0  = (const float*)d_in[1];
  const float* c0  = (const float*)d_in[2];
  const float* Wx0 = (const float*)d_in[3];
  const float* Wh0 = (const float*)d_in[4];
  const float* bx0 = (const float*)d_in[5];
  const float* bh0 = (const float*)d_in[6];
  const float* Wx1 = (const float*)d_in[7];
  const float* Wh1 = (const float*)d_in[8];
  const float* bx1 = (const float*)d_in[9];
  const float* bh1 = (const float*)d_in[10];

  char* ws = (char*)d_ws;
  short* hb1  = (short*)(ws + HB1_OFF);
  int* flags  = (int*)(ws + FLAGS_OFF);
  short* hs   = (short*)(ws + HS_OFF);
  short* xb   = (short*)(ws + XB_OFF);

  float* yout = (float*)d_out;
  float* hfin = yout + (size_t)T_STEPS * BH;
  float* cfin = hfin + 2 * BH;

  hipMemsetAsync(flags, 0, (size_t)2 * T_STEPS * NBLK_L * sizeof(int), stream);
  prep_xb<<<(int)(((size_t)T_STEPS * BH / 8 + 255) / 256), 256, 0, stream>>>(x, xb);
  prep_h<<<(2 * BH + 255) / 256, 256, 0, stream>>>(h0, hs, hb1);

  KArgs ka{xb, c0, Wx0, Wh0, bx0, bh0, Wx1, Wh1, bx1, bh1,
           hs, hb1, flags, yout, hfin, cfin};
  void* params[] = {&ka};
  hipLaunchCooperativeKernel((void*)lstm_fused, dim3(NBLK), dim3(TPB), params, 0,
                             stream);
}

// Round 6
// 16495.840 us; speedup vs baseline: 4.1204x; 1.0204x over previous
//
// LSTM 2-layer fused persistent kernel — Round 6.
// R5 post-mortem: no spill (weights in AGPR; VGPR_Count=arch only). 8.2us/tick
// = latency chain; WRITE_SIZE 3x expected -> sc0sc1 write-through stores ack
// from HBM (~1.3us) and sit on the critical path before each flag. Fixes:
// (1) publish h + flags via global_atomic_swap[_x2] sc1 (executes & acks at
//     MALL, readers bypass caches -> coherent, fast ack);
// (2) Wx -> LDS so Wh-only in AGPR; two frags fit -> fragX/fragH loads
//     overlap via vmcnt(16)/vmcnt(0) phasing (hides one MALL round trip);
// (3) RING 16->64: L0 free-runs, only L1 self-loop paces.
// ws: hb1 128KB | flags 2MB | hs-ring 4MB | xb 128MB (~140.6 MB)
#include <hip/hip_runtime.h>
#include <hip/hip_bf16.h>
#include <cstdint>
#include <cstddef>

#define T_STEPS 2048
#define BATCH   64
#define HID     512
#define BH      (BATCH * HID)     // 32768
#define NBLK    256               // 2 layers x 128 blocks (16 gate-rows each)
#define TPB     256               // 4 waves: batch split 4 x 16
#define NBLK_L  128               // blocks per layer
#define RING    64                // layer0 h ring slots (pow2)

typedef float        f32x4 __attribute__((ext_vector_type(4)));
typedef short        s16x8 __attribute__((ext_vector_type(8)));
typedef int          i32x4 __attribute__((ext_vector_type(4)));
typedef unsigned int u32x2 __attribute__((ext_vector_type(2)));

// ---- ws offsets (bytes) ----
#define HB1_OFF   0x000000u   // [2 parity][64][512] bf16 = 128 KiB
#define FLAGS_OFF 0x020000u   // 2 * 2048 * 128 * 4 = 2 MiB
#define HS_OFF    0x230000u   // [RING][64][512] bf16 = 4 MiB
#define XB_OFF    0x640000u   // [T][64][512] bf16 = 128 MiB
// end = 0x8640000 = 140.6 MB

static __device__ __forceinline__ short f2bf(float v) {
  __hip_bfloat16 b = __float2bfloat16(v);
  return *reinterpret_cast<short*>(&b);
}
static __device__ __forceinline__ float sigm(float x) {
  return 1.0f / (1.0f + __expf(-x));
}

// coherent (cache-bypass -> MALL) 16B load; batch issue, wait separately
#define LOADC16(dst, base, off)                                        \
  asm volatile("global_load_dwordx4 %0, %1, off offset:%c2 sc0 sc1"    \
               : "=v"(dst) : "v"(base), "i"(off))
// cached 16B load (L1/L2 path) with controlled issue order / vmcnt count
#define LOADP16(dst, base, off)                                        \
  asm volatile("global_load_dwordx4 %0, %1, off offset:%c2"            \
               : "=v"(dst) : "v"(base), "i"(off))
// publish 8B at MALL: atomic swap, no return, device scope
#define ATOMPUB8(base, val)                                            \
  asm volatile("global_atomic_swap_x2 %0, %1, off sc1"                 \
               :: "v"(base), "v"(val) : "memory")
#define VMDRAIN  asm volatile("s_waitcnt vmcnt(0)" ::: "memory")
#define VMWAIT16 asm volatile("s_waitcnt vmcnt(16)" ::: "memory")

#define MFMA(acc, af, bf) \
  acc = __builtin_amdgcn_mfma_f32_16x16x32_bf16(af, bf, acc, 0, 0, 0)

// spin on 4 flags (one dwordx4) until all nonzero
static __device__ __forceinline__ void poll4(const int* p) {
  i32x4 v;
  for (;;) {
    asm volatile("global_load_dwordx4 %0, %1, off sc0 sc1\n\t"
                 "s_waitcnt vmcnt(0)"
                 : "=v"(v) : "v"(p) : "memory");
    if ((v[0] & v[1] & v[2] & v[3]) != 0) return;
    __builtin_amdgcn_s_sleep(1);
  }
}

__global__ void prep_h(const float* __restrict__ h0, short* __restrict__ hs,
                       short* __restrict__ hb1) {
  int idx = blockIdx.x * blockDim.x + threadIdx.x;
  if (idx >= 2 * BH) return;
  short v = f2bf(h0[idx]);
  if (idx < BH) hs[idx] = v;          // hs ring slot 0 = layer0 initial h
  else hb1[idx - BH] = v;             // hb1 parity-0 = layer1 initial h
}

__global__ void prep_xb(const float* __restrict__ x, short* __restrict__ xb) {
  size_t i = ((size_t)blockIdx.x * blockDim.x + threadIdx.x) * 8;
  if (i >= (size_t)T_STEPS * BH) return;
  f32x4 v0 = *reinterpret_cast<const f32x4*>(x + i);
  f32x4 v1 = *reinterpret_cast<const f32x4*>(x + i + 4);
  s16x8 o;
  o[0] = f2bf(v0[0]); o[1] = f2bf(v0[1]); o[2] = f2bf(v0[2]); o[3] = f2bf(v0[3]);
  o[4] = f2bf(v1[0]); o[5] = f2bf(v1[1]); o[6] = f2bf(v1[2]); o[7] = f2bf(v1[3]);
  *reinterpret_cast<s16x8*>(xb + i) = o;
}

struct KArgs {
  const short* xb;   // [T][B][H] bf16
  const float* c0;
  const float *Wx0, *Wh0, *bx0, *bh0;
  const float *Wx1, *Wh1, *bx1, *bh1;
  short* hs;      // [RING][B][H] bf16; slot t&63 = layer0 h at time t
  short* hb1;     // [2][B][H] bf16 (layer1 h double buffer)
  int* flags;     // [2][T][128]
  float *yout, *hfin, *cfin;
};

template <int LAY>
static __device__ __forceinline__ void run_layer(const KArgs& a, int bidL,
                                                 int tid, short (*wl)[520]) {
  const int nt = tid >> 6;                        // batch tile 0..3
  const int l = tid & 63, lane15 = l & 15, jloc = l >> 4, koff = jloc * 8;
  const int row0 = bidL * 16;                     // gate-interleaved row base
  const int b = nt * 16 + lane15;                 // batch this lane owns
  const int kbase = row0 >> 2;                    // first h-col of this block
  const int kcol = kbase + jloc;                  // h-col this lane owns

  const float* WxL = LAY ? a.Wx1 : a.Wx0;
  const float* WhL = LAY ? a.Wh1 : a.Wh0;
  const float* bxL = LAY ? a.bx1 : a.bx0;
  const float* bhL = LAY ? a.bh1 : a.bh0;

  // ---- one-time: Wx -> LDS (16 rows x 512, pad 8 shorts -> 2-way banks) ----
  {
    const int rloc = tid >> 4;                    // 0..15
    const int col0 = (tid & 15) * 32;             // 0..480
    const int rr = row0 + rloc;
    const int sr = (rr & 3) * HID + (rr >> 2);
    const float* wsrc = WxL + (size_t)sr * 512 + col0;
#pragma unroll
    for (int i = 0; i < 4; ++i) {
      f32x4 v0 = *reinterpret_cast<const f32x4*>(wsrc + i * 8);
      f32x4 v1 = *reinterpret_cast<const f32x4*>(wsrc + i * 8 + 4);
      s16x8 wv;
      wv[0] = f2bf(v0[0]); wv[1] = f2bf(v0[1]); wv[2] = f2bf(v0[2]); wv[3] = f2bf(v0[3]);
      wv[4] = f2bf(v1[0]); wv[5] = f2bf(v1[1]); wv[6] = f2bf(v1[2]); wv[7] = f2bf(v1[3]);
      *reinterpret_cast<s16x8*>(&wl[rloc][col0 + i * 8]) = wv;
    }
  }
  // ---- one-time: Wh -> regs (AGPR-friendly: only 64 regs) ----
  const int r = row0 + lane15;
  const int sr2 = (r & 3) * HID + (r >> 2);
  s16x8 whreg[16];
#pragma unroll
  for (int ks = 0; ks < 16; ++ks) {
    const float* src = WhL + (size_t)sr2 * 512 + ks * 32 + koff;
    f32x4 v0 = *reinterpret_cast<const f32x4*>(src);
    f32x4 v1 = *reinterpret_cast<const f32x4*>(src + 4);
    s16x8 wv;
    wv[0] = f2bf(v0[0]); wv[1] = f2bf(v0[1]); wv[2] = f2bf(v0[2]); wv[3] = f2bf(v0[3]);
    wv[4] = f2bf(v1[0]); wv[5] = f2bf(v1[1]); wv[6] = f2bf(v1[2]); wv[7] = f2bf(v1[3]);
    whreg[ks] = wv;
  }
  const float bI = bxL[kcol]           + bhL[kcol];
  const float bF = bxL[HID + kcol]     + bhL[HID + kcol];
  const float bG = bxL[2 * HID + kcol] + bhL[2 * HID + kcol];
  const float bO = bxL[3 * HID + kcol] + bhL[3 * HID + kcol];
  float c = a.c0[LAY * BH + b * HID + kcol];

  int* f0 = a.flags;                             // [T][128] layer0 flags
  int* f1 = a.flags + (size_t)T_STEPS * NBLK_L;  // layer1 flags
  __syncthreads();

  for (int t = 0; t < T_STEPS; ++t) {
    // ---- wait for producers (parallel distinct-flag polls, no RMW) ----
    if (LAY == 0) {
      if (t > 0 && tid < 32) poll4(f0 + (size_t)(t - 1) * NBLK_L + tid * 4);
      if (t >= RING && tid >= 32 && tid < 64)    // ring-slot reuse throttle
        poll4(f1 + (size_t)(t - RING) * NBLK_L + (tid - 32) * 4);
    } else {
      if (tid < 32) poll4(f0 + (size_t)t * NBLK_L + tid * 4);    // x ready
      else if (t > 0 && tid < 64)
        poll4(f1 + (size_t)(t - 1) * NBLK_L + (tid - 32) * 4);   // own h ready
    }
    __syncthreads();

    f32x4 acc0 = {0.f, 0.f, 0.f, 0.f}, acc1 = {0.f, 0.f, 0.f, 0.f};
    s16x8 fragX[16], fragH[16];

    // issue fragX loads FIRST (oldest 16 in vmcnt), then fragH
    if (LAY == 0) {
      const short* xp = a.xb + ((size_t)t * BATCH + b) * HID + koff;
#pragma unroll
      for (int i = 0; i < 16; ++i) LOADP16(fragX[i], xp, i * 64);   // cached
    } else {
      const short* xp = a.hs + (size_t)((t + 1) & (RING - 1)) * BH
                        + b * HID + koff;
#pragma unroll
      for (int i = 0; i < 16; ++i) LOADC16(fragX[i], xp, i * 64);   // coherent
    }
    const short* hp = (LAY ? a.hb1 + (t & 1) * BH
                           : a.hs + (size_t)(t & (RING - 1)) * BH)
                      + b * HID + koff;
#pragma unroll
    for (int i = 0; i < 16; ++i) LOADC16(fragH[i], hp, i * 64);     // coherent

    VMWAIT16;                               // fragX complete (fragH in flight)
    __builtin_amdgcn_sched_barrier(0);
#pragma unroll
    for (int ks = 0; ks < 16; ++ks) {       // A-operand streamed from LDS
      s16x8 axf = *reinterpret_cast<const s16x8*>(&wl[lane15][ks * 32 + koff]);
      if (ks & 1) { MFMA(acc1, axf, fragX[ks]); } else { MFMA(acc0, axf, fragX[ks]); }
    }
    VMDRAIN;                                // fragH complete
    __builtin_amdgcn_sched_barrier(0);
#pragma unroll
    for (int ks = 0; ks < 16; ++ks) {
      if (ks & 1) { MFMA(acc1, whreg[ks], fragH[ks]); } else { MFMA(acc0, whreg[ks], fragH[ks]); }
    }

    // lane's 4 acc regs = gates (i,f,g,o) of its (b,kcol)
    float gi = acc0[0] + acc1[0] + bI;
    float gf = acc0[1] + acc1[1] + bF;
    float gg = acc0[2] + acc1[2] + bG;
    float go = acc0[3] + acc1[3] + bO;
    float iv = sigm(gi), fv = sigm(gf);
    float gv = tanhf(gg), ov = sigm(go);
    c = fv * c + iv * gv;
    float hv = ov * tanhf(c);

    // pack 4 consecutive kcols (jloc 0..3, same b) into jloc0 lane -> 8B
    int hvi = (int)(unsigned short)f2bf(hv);
    int h1 = __shfl(hvi, lane15 + 16);
    int h2 = __shfl(hvi, lane15 + 32);
    int h3 = __shfl(hvi, lane15 + 48);
    short* dsth = (LAY ? a.hb1 + ((t + 1) & 1) * BH
                       : a.hs + (size_t)((t + 1) & (RING - 1)) * BH)
                  + b * HID + kbase;
    if (jloc == 0) {
      u32x2 pk;
      pk[0] = (unsigned)(hvi & 0xffff) | ((unsigned)h1 << 16);
      pk[1] = (unsigned)(h2 & 0xffff) | ((unsigned)h3 << 16);
      ATOMPUB8(dsth, pk);                   // publish at MALL, ack from MALL
    }
    if (LAY == 1) {
      int y0 = __float_as_int(hv);
      int y1 = __shfl(y0, lane15 + 16);
      int y2 = __shfl(y0, lane15 + 32);
      int y3 = __shfl(y0, lane15 + 48);
      if (jloc == 0) {
        f32x4 yv = {__int_as_float(y0), __int_as_float(y1),
                    __int_as_float(y2), __int_as_float(y3)};
        __builtin_nontemporal_store(
            yv, reinterpret_cast<f32x4*>(a.yout + ((size_t)t * BATCH + b) * HID + kbase));
      }
    }
    if (t == T_STEPS - 1) {
      a.hfin[LAY * BH + b * HID + kcol] = hv;
      a.cfin[LAY * BH + b * HID + kcol] = c;
    }

    // ---- release: wait MALL acks, then flag (atomic -> lands at MALL) ----
    VMDRAIN;
    __syncthreads();
    if (tid == 0) {
      int one = 1;
      int* fp = (LAY ? f1 : f0) + (size_t)t * NBLK_L + bidL;
      asm volatile("global_atomic_swap %0, %1, off sc1"
                   :: "v"(fp), "v"(one) : "memory");
    }
  }
}

__global__ __launch_bounds__(TPB, 2) void lstm_fused(KArgs a) {
  __shared__ short wl[16][520];             // Wx tile, padded (2-way banks)
  const int bid = blockIdx.x;
  if (bid < NBLK_L) run_layer<0>(a, bid, threadIdx.x, wl);
  else              run_layer<1>(a, bid - NBLK_L, threadIdx.x, wl);
}

// ---------------- host launch ----------------
extern "C" void kernel_launch(void* const* d_in, const int* in_sizes, int n_in,
                              void* d_out, int out_size, void* d_ws, size_t ws_size,
                              hipStream_t stream) {
  const float* x   = (const float*)d_in[0];
  const float* h0  = (const float*)d_in[1];
  const float* c0  = (const float*)d_in[2];
  const float* Wx0 = (const float*)d_in[3];
  const float* Wh0 = (const float*)d_in[4];
  const float* bx0 = (const float*)d_in[5];
  const float* bh0 = (const float*)d_in[6];
  const float* Wx1 = (const float*)d_in[7];
  const float* Wh1 = (const float*)d_in[8];
  const float* bx1 = (const float*)d_in[9];
  const float* bh1 = (const float*)d_in[10];

  char* ws = (char*)d_ws;
  short* hb1  = (short*)(ws + HB1_OFF);
  int* flags  = (int*)(ws + FLAGS_OFF);
  short* hs   = (short*)(ws + HS_OFF);
  short* xb   = (short*)(ws + XB_OFF);

  float* yout = (float*)d_out;
  float* hfin = yout + (size_t)T_STEPS * BH;
  float* cfin = hfin + 2 * BH;

  hipMemsetAsync(flags, 0, (size_t)2 * T_STEPS * NBLK_L * sizeof(int), stream);
  prep_xb<<<(int)(((size_t)T_STEPS * BH / 8 + 255) / 256), 256, 0, stream>>>(x, xb);
  prep_h<<<(2 * BH + 255) / 256, 256, 0, stream>>>(h0, hs, hb1);

  KArgs ka{xb, c0, Wx0, Wh0, bx0, bh0, Wx1, Wh1, bx1, bh1,
           hs, hb1, flags, yout, hfin, cfin};
  void* params[] = {&ka};
  hipLaunchCooperativeKernel((void*)lstm_fused, dim3(NBLK), dim3(TPB), params, 0,
                             stream);
}